// Round 7
// baseline (710.882 us; speedup 1.0000x reference)
//
#include <hip/hip_runtime.h>
#include <stdint.h>

// RoPE attention, full bf16-MFMA pipeline (fp32 accumulate everywhere).
// B=4 T=2048 HID=2048 NH=16 HD=128. Output fp32.

typedef unsigned short u16;
typedef unsigned int   u32;
typedef unsigned long long u64;
typedef __attribute__((ext_vector_type(8))) short short8;   // 8 x bf16 (4 VGPRs)
typedef __attribute__((ext_vector_type(4))) float f32x4;    // MFMA accumulator

__device__ __forceinline__ void gload16(const void* g, void* l) {
  // async global->LDS, 16B/lane; LDS dest is wave-uniform base + lane*16
  __builtin_amdgcn_global_load_lds((const __attribute__((address_space(1))) void*)g,
                                   (__attribute__((address_space(3))) void*)l, 16, 0, 0);
}

__device__ __forceinline__ u16 f2bf(float f) {
  u32 u = __builtin_bit_cast(u32, f);
  u32 r = (u + 0x7fffu + ((u >> 16) & 1u)) >> 16;  // RNE
  return (u16)r;
}
__device__ __forceinline__ float bf2f(u16 b) {
  u32 u = ((u32)b) << 16;
  return __builtin_bit_cast(float, u);
}

// ---------------------------------------------------------------- converts
__global__ __launch_bounds__(256) void cvt_kernel(const float* __restrict__ src,
                                                  u16* __restrict__ dst) {
  size_t i = ((size_t)blockIdx.x * 256 + threadIdx.x) * 4;
  f32x4 v = *(const f32x4*)(src + i);
  u64 pk = (u64)f2bf(v[0]) | ((u64)f2bf(v[1]) << 16) |
           ((u64)f2bf(v[2]) << 32) | ((u64)f2bf(v[3]) << 48);
  *(u64*)(dst + i) = pk;
}

// ---------------------------------------------------------------- NT GEMM
// C[M,N] = A[M,K] * B[N,K]^T, bf16 inputs, fp32 accum.
// 128x128 block tile, BK=32, 4 waves (2x2), 4x4 16x16x32 MFMA tiles/wave.
// Chunk-level XOR swizzle (both-sides, LOOP-INVARIANT): within each 16-row
// x 64B LDS chunk, slot s of row r holds global k-slot s^(r&3).
//   write: global source col = ((lane&3)^(lrow&3))*8, LDS dest stays linear
//   read : byte off = (quad*16) ^ ((l16&3)<<4)  [per-thread constant]
// -> fragment ds_read_b128 4-way conflict becomes 2-way (free).
// MODE 0: bf16 out. MODE 1: f32 out + bias.
template <int MODE>
__global__ __launch_bounds__(256, 2) void gemm_bt(const u16* __restrict__ A,
                                                  const u16* __restrict__ B,
                                                  void* __restrict__ C,
                                                  int M, int N, int K,
                                                  const float* __restrict__ bias) {
  __shared__ __attribute__((aligned(16))) u16 As[128 * 32];
  __shared__ __attribute__((aligned(16))) u16 Bs[128 * 32];
  const int tid  = threadIdx.x;
  const int wave = tid >> 6, lane = tid & 63;
  const int quad = lane >> 4, l16 = lane & 15;
  const int m0 = blockIdx.y * 128, n0 = blockIdx.x * 128;
  const int wr = wave >> 1, wc = wave & 1;
  const int lrow = lane >> 2;                        // 0..15 row within chunk
  const int lcol = (((lane & 3) ^ (lrow & 3)) * 8);  // swizzled source k-slot
  const int rswz = (l16 & 3) << 4;                   // read-side XOR (bytes)
  f32x4 acc[4][4] = {};

  const size_t Abase = (size_t)(m0 + wave * 32 + lrow) * K + lcol;
  const size_t Bbase = (size_t)(n0 + wave * 32 + lrow) * K + lcol;

  for (int k0 = 0; k0 < K; k0 += 32) {
    gload16(A + Abase + k0,                 &As[(wave * 32) * 32]);
    gload16(A + Abase + (size_t)16 * K + k0, &As[(wave * 32 + 16) * 32]);
    gload16(B + Bbase + k0,                 &Bs[(wave * 32) * 32]);
    gload16(B + Bbase + (size_t)16 * K + k0, &Bs[(wave * 32 + 16) * 32]);
    __syncthreads();
    short8 a[4], b[4];
#pragma unroll
    for (int rt = 0; rt < 4; rt++)
      a[rt] = *(const short8*)((const char*)As + (wr * 64 + rt * 16 + l16) * 64 + ((quad * 16) ^ rswz));
#pragma unroll
    for (int ct = 0; ct < 4; ct++)
      b[ct] = *(const short8*)((const char*)Bs + (wc * 64 + ct * 16 + l16) * 64 + ((quad * 16) ^ rswz));
#pragma unroll
    for (int rt = 0; rt < 4; rt++)
#pragma unroll
      for (int ct = 0; ct < 4; ct++)
        acc[rt][ct] = __builtin_amdgcn_mfma_f32_16x16x32_bf16(a[rt], b[ct], acc[rt][ct], 0, 0, 0);
    __syncthreads();
  }
  // epilogue: C-layout col=lane&15, row=quad*4+reg (verified m89/m91)
#pragma unroll
  for (int rt = 0; rt < 4; rt++) {
#pragma unroll
    for (int ct = 0; ct < 4; ct++) {
      const int col = n0 + wc * 64 + ct * 16 + l16;
      float bv = (MODE == 1) ? bias[col] : 0.0f;
#pragma unroll
      for (int r = 0; r < 4; r++) {
        const int row = m0 + wr * 64 + rt * 16 + quad * 4 + r;
        if (MODE == 0)
          ((u16*)C)[(size_t)row * N + col] = f2bf(acc[rt][ct][r]);
        else
          ((float*)C)[(size_t)row * N + col] = acc[rt][ct][r] + bv;
      }
    }
  }
}

// ---------------------------------------------------------------- RoPE + reshape
// qkv[8192][6144] bf16 -> Qr/Kr [bh][t][d] (Q pre-scaled by 1/sqrt(HD), both RoPE'd),
// Vt [bh][d][t] (transposed via LDS).
__global__ __launch_bounds__(256) void rope_reshape(const u16* __restrict__ qkv,
                                                    const float* __restrict__ cosb,
                                                    const float* __restrict__ sinb,
                                                    u16* __restrict__ Qr,
                                                    u16* __restrict__ Kr,
                                                    u16* __restrict__ Vt) {
  __shared__ __attribute__((aligned(16))) u16 Vl[32 * 132];  // 32 t rows, stride 132 (pad)
  const int tb = blockIdx.x;   // t-block of 32 (0..63)
  const int bh = blockIdx.y;   // b*16+h (0..63)
  const int tid = threadIdx.x;
  const int b = bh >> 4, h = bh & 15;
  const float scale = 0.08838834764831845f;  // 1/sqrt(128)
#pragma unroll
  for (int p8 = 0; p8 < 8; p8++) {
    int p = p8 * 256 + tid;
    int r = p >> 6, i = p & 63;      // row within block, pair index
    int t = tb * 32 + r;
    size_t base = (size_t)(b * 2048 + t) * 6144 + h * 128 + 2 * i;
    float c = cosb[t * 64 + i], s = sinb[t * 64 + i];
    u32 q2 = *(const u32*)(qkv + base);
    float qe = bf2f((u16)q2), qo = bf2f((u16)(q2 >> 16));
    u32 qw = (u32)f2bf((qe * c - qo * s) * scale) | ((u32)f2bf((qe * s + qo * c) * scale) << 16);
    *(u32*)(Qr + ((size_t)bh * 2048 + t) * 128 + 2 * i) = qw;
    u32 k2 = *(const u32*)(qkv + base + 2048);
    float ke = bf2f((u16)k2), ko = bf2f((u16)(k2 >> 16));
    u32 kw = (u32)f2bf(ke * c - ko * s) | ((u32)f2bf(ke * s + ko * c) << 16);
    *(u32*)(Kr + ((size_t)bh * 2048 + t) * 128 + 2 * i) = kw;
    u32 v2 = *(const u32*)(qkv + base + 4096);
    *(u32*)&Vl[r * 132 + 2 * i] = v2;
  }
  __syncthreads();
#pragma unroll
  for (int u8 = 0; u8 < 8; u8++) {
    int u = u8 * 256 + tid;
    int d = u >> 4, tp = (u & 15) * 2;  // 128 d, 16 t-pairs
    u32 lo = Vl[tp * 132 + d];
    u32 hi = Vl[(tp + 1) * 132 + d];
    *(u32*)(Vt + ((size_t)bh * 128 + d) * 2048 + tb * 32 + tp) = lo | (hi << 16);
  }
}

// ---------------------------------------------------------------- flash attention
// One block = 128 Q rows (4 waves x 32), loops over 16 KV blocks of 128.
// K/V staged via global_load_lds gather into fragment-chunked LDS
// (chunk = 16 rows x 32 k, row stride 64B), with the same chunk-level
// LOOP-INVARIANT XOR swizzle as gemm_bt (slot s of row r <- global slot
// s^(r&3); source col pre-swizzled, linear LDS dest, read XOR hoisted)
// -> kf/vf ds_read_b128 4-way conflicts become 2-way (free).
// P (exp scores) aliases K region with PADDED stride 136 el (R6 verified).
// All hot-loop addressing AFFINE or hoisted-constant-XOR only (rounds
// 1/2/4 lesson: per-iteration XOR here tips a spill cliff).
// T13 defer-max (R5/R6 verified): gated max-reduce + rescale.
__global__ __launch_bounds__(256, 2) void flash_attn(const u16* __restrict__ Q,
                                                     const u16* __restrict__ K,
                                                     const u16* __restrict__ Vt,
                                                     u16* __restrict__ Out) {
  __shared__ __attribute__((aligned(16))) char lds[67584];  // K 32KB | gap | V 32KB
  u16* Klds = (u16*)lds;                  // 32 chunks x 512 el
  u16* Vlds = (u16*)(lds + 34816);        // 32 chunks x 512 el
  const int qb = blockIdx.x;   // 0..15
  const int bh = blockIdx.y;   // 0..63
  const int tid = threadIdx.x;
  const int wave = tid >> 6, lane = tid & 63;
  const int quad = lane >> 4, l16 = lane & 15;
  const int lrow4 = lane >> 2;
  const int lcol8 = (((lane & 3) ^ (lrow4 & 3)) * 8);  // swizzled source k-slot
  const int rswz = (l16 & 3) << 4;                     // read-side XOR (bytes)
  const u16* Qh = Q + (size_t)bh * 2048 * 128;
  const u16* Kh = K + (size_t)bh * 2048 * 128;
  const u16* Vh = Vt + (size_t)bh * 128 * 2048;

  // Q fragments (A-layout: m=lane&15, k=quad*8+j), kept in regs, pre-scaled
  short8 qf[2][4];
#pragma unroll
  for (int rt = 0; rt < 2; rt++)
#pragma unroll
    for (int kk = 0; kk < 4; kk++)
      qf[rt][kk] = *(const short8*)(Qh + (size_t)(qb * 128 + wave * 32 + rt * 16 + l16) * 128 + kk * 32 + quad * 8);

  f32x4 o[2][8] = {};
  float mrow[2][4], lrowv[2][4];
#pragma unroll
  for (int rt = 0; rt < 2; rt++)
#pragma unroll
    for (int r = 0; r < 4; r++) { mrow[rt][r] = -1e30f; lrowv[rt][r] = 0.f; }

  for (int kb = 0; kb < 16; kb++) {
    __syncthreads();  // all P/V reads from previous iter done
#pragma unroll
    for (int c = 0; c < 8; c++) {
      int ch = wave * 8 + c;
      int tbb = ch >> 2, kk = ch & 3;  // 16-row group, 32-k group
      gload16(Kh + (size_t)(kb * 128 + tbb * 16 + lrow4) * 128 + kk * 32 + lcol8, &Klds[ch * 512]);
      gload16(Vh + (size_t)(tbb * 16 + lrow4) * 2048 + kb * 128 + kk * 32 + lcol8, &Vlds[ch * 512]);
    }
    __syncthreads();  // K/V staged

    // S = Q K^T  (32 rows x 128 cols per wave)
    f32x4 s[2][8];
#pragma unroll
    for (int nt = 0; nt < 8; nt++) {
      short8 kf[4];
#pragma unroll
      for (int kk = 0; kk < 4; kk++)
        kf[kk] = *(const short8*)((const char*)Klds + (nt * 4 + kk) * 1024 + l16 * 64 + ((quad * 16) ^ rswz));
#pragma unroll
      for (int rt = 0; rt < 2; rt++) {
        f32x4 a = {};
#pragma unroll
        for (int kk = 0; kk < 4; kk++)
          a = __builtin_amdgcn_mfma_f32_16x16x32_bf16(qf[rt][kk], kf[kk], a, 0, 0, 0);
        s[rt][nt] = a;
      }
    }

    // online softmax with T13 defer-max (C-layout: row=quad*4+reg, col=nt*16+l16);
    // gate on the pre-reduce local max: skips the 4-shuffle reduce too.
#pragma unroll
    for (int rt = 0; rt < 2; rt++)
#pragma unroll
      for (int r = 0; r < 4; r++) {
        float mx8 = s[rt][0][r];
#pragma unroll
        for (int nt = 1; nt < 8; nt++) mx8 = fmaxf(mx8, s[rt][nt][r]);
        if (__any(mx8 > mrow[rt][r] + 8.0f)) {
          float mx = mx8;
          mx = fmaxf(mx, __shfl_xor(mx, 1));
          mx = fmaxf(mx, __shfl_xor(mx, 2));
          mx = fmaxf(mx, __shfl_xor(mx, 4));
          mx = fmaxf(mx, __shfl_xor(mx, 8));
          float mnew = fmaxf(mrow[rt][r], mx);
          float alpha = __expf(mrow[rt][r] - mnew);
          mrow[rt][r] = mnew;
          lrowv[rt][r] *= alpha;
#pragma unroll
          for (int dt = 0; dt < 8; dt++) o[rt][dt][r] *= alpha;
        }
        float m = mrow[rt][r];
        float sum = 0.f;
#pragma unroll
        for (int nt = 0; nt < 8; nt++) {
          float p = __expf(s[rt][nt][r] - m);   // bounded by e^8
          s[rt][nt][r] = p;
          sum += p;
        }
        sum += __shfl_xor(sum, 1);
        sum += __shfl_xor(sum, 2);
        sum += __shfl_xor(sum, 4);
        sum += __shfl_xor(sum, 8);
        lrowv[rt][r] += sum;
      }

    __syncthreads();  // all waves done reading Klds before P overwrite
    // P: 32 rows x 128 k per wave, PADDED stride 136 el (affine: shl+add)
    u16* P = (u16*)lds + wave * 4352;   // 8704B/wave, 4 waves = 34816B
#pragma unroll
    for (int rt = 0; rt < 2; rt++)
#pragma unroll
      for (int nt = 0; nt < 8; nt++)
#pragma unroll
        for (int r = 0; r < 4; r++)
          P[(rt * 16 + quad * 4 + r) * 136 + nt * 16 + l16] = f2bf(s[rt][nt][r]);
    __syncthreads();  // P visible

    // O += P V  (A = P from LDS, B = V fragments)
#pragma unroll
    for (int kk = 0; kk < 4; kk++) {
      short8 pf[2];
#pragma unroll
      for (int rt = 0; rt < 2; rt++)
        pf[rt] = *(const short8*)&P[(rt * 16 + l16) * 136 + kk * 32 + quad * 8];
#pragma unroll
      for (int dt = 0; dt < 8; dt++) {
        short8 vf = *(const short8*)((const char*)Vlds + (dt * 4 + kk) * 1024 + l16 * 64 + ((quad * 16) ^ rswz));
#pragma unroll
        for (int rt = 0; rt < 2; rt++)
          o[rt][dt] = __builtin_amdgcn_mfma_f32_16x16x32_bf16(pf[rt], vf, o[rt][dt], 0, 0, 0);
      }
    }
  }

  // epilogue: divide by l, store attn_out [b*T+t][h*128+d] bf16
  const int b = bh >> 4, h = bh & 15;
#pragma unroll
  for (int rt = 0; rt < 2; rt++) {
    float inv[4];
#pragma unroll
    for (int r = 0; r < 4; r++) inv[r] = 1.0f / lrowv[rt][r];
#pragma unroll
    for (int dt = 0; dt < 8; dt++) {
      int d = dt * 16 + l16;
#pragma unroll
      for (int r = 0; r < 4; r++) {
        int t = qb * 128 + wave * 32 + rt * 16 + quad * 4 + r;
        Out[((size_t)(b * 2048 + t)) * 2048 + h * 128 + d] = f2bf(o[rt][dt][r] * inv[r]);
      }
    }
  }
}

// ---------------------------------------------------------------- launch
extern "C" void kernel_launch(void* const* d_in, const int* in_sizes, int n_in,
                              void* d_out, int out_size, void* d_ws, size_t ws_size,
                              hipStream_t stream) {
  const float* x      = (const float*)d_in[0];
  const float* w_qkv  = (const float*)d_in[1];
  const float* w_proj = (const float*)d_in[2];
  const float* b_proj = (const float*)d_in[3];
  const float* cosb   = (const float*)d_in[4];
  const float* sinb   = (const float*)d_in[5];
  char* ws = (char*)d_ws;
  const size_t MB = 1024 * 1024;
  // lifetime-aliased layout, peak 200 MB:
  u16* xb   = (u16*)(ws + 0);         // x bf16, 32MB (dead after GEMM1)
  u16* Qr   = (u16*)(ws + 0);         // aliases xb
  u16* wqb  = (u16*)(ws + 32 * MB);   // w_qkv bf16, 24MB (dead after GEMM1)
  u16* Kr   = (u16*)(ws + 32 * MB);   // 32MB, aliases wqb (+pad)
  u16* qkv  = (u16*)(ws + 64 * MB);   // 96MB (dead after reshape)
  u16* attn = (u16*)(ws + 64 * MB);   // 32MB, aliases qkv
  u16* Vt   = (u16*)(ws + 160 * MB);  // 32MB
  u16* wpb  = (u16*)(ws + 192 * MB);  // w_proj bf16, 8MB

  cvt_kernel<<<16384, 256, 0, stream>>>(x, xb);        // 16.8M elems
  cvt_kernel<<<12288, 256, 0, stream>>>(w_qkv, wqb);   // 12.6M
  cvt_kernel<<<4096, 256, 0, stream>>>(w_proj, wpb);   // 4.2M

  gemm_bt<0><<<dim3(48, 64), 256, 0, stream>>>(xb, wqb, qkv, 8192, 6144, 2048, nullptr);
  rope_reshape<<<dim3(64, 64), 256, 0, stream>>>(qkv, cosb, sinb, Qr, Kr, Vt);
  flash_attn<<<dim3(16, 64), 256, 0, stream>>>(Qr, Kr, Vt, attn);
  gemm_bt<1><<<dim3(16, 64), 256, 0, stream>>>(attn, wpb, (float*)d_out, 8192, 2048, 2048, b_proj);
}

// Round 8
// 692.097 us; speedup vs baseline: 1.0271x; 1.0271x over previous
//
#include <hip/hip_runtime.h>
#include <stdint.h>

// RoPE attention, full bf16-MFMA pipeline (fp32 accumulate everywhere).
// B=4 T=2048 HID=2048 NH=16 HD=128. Output fp32.

typedef unsigned short u16;
typedef unsigned int   u32;
typedef unsigned long long u64;
typedef __attribute__((ext_vector_type(8))) short short8;   // 8 x bf16 (4 VGPRs)
typedef __attribute__((ext_vector_type(4))) float f32x4;    // MFMA accumulator

__device__ __forceinline__ void gload16(const void* g, void* l) {
  // async global->LDS, 16B/lane; LDS dest is wave-uniform base + lane*16
  __builtin_amdgcn_global_load_lds((const __attribute__((address_space(1))) void*)g,
                                   (__attribute__((address_space(3))) void*)l, 16, 0, 0);
}

__device__ __forceinline__ u16 f2bf(float f) {
  u32 u = __builtin_bit_cast(u32, f);
  u32 r = (u + 0x7fffu + ((u >> 16) & 1u)) >> 16;  // RNE
  return (u16)r;
}
__device__ __forceinline__ float bf2f(u16 b) {
  u32 u = ((u32)b) << 16;
  return __builtin_bit_cast(float, u);
}

// ---------------------------------------------------------------- converts
__global__ __launch_bounds__(256) void cvt_kernel(const float* __restrict__ src,
                                                  u16* __restrict__ dst) {
  size_t i = ((size_t)blockIdx.x * 256 + threadIdx.x) * 4;
  f32x4 v = *(const f32x4*)(src + i);
  u64 pk = (u64)f2bf(v[0]) | ((u64)f2bf(v[1]) << 16) |
           ((u64)f2bf(v[2]) << 32) | ((u64)f2bf(v[3]) << 48);
  *(u64*)(dst + i) = pk;
}

// ---------------------------------------------------------------- fused GEMM1
// qkv = x[8192,2048] * w_qkv[6144,2048]^T with RoPE+reshape fused into the
// epilogue (R6-proven K-loop, R0 affine addressing; counters show the
// 2.5e7 conflict count is free 2-way aliasing — not worth chasing).
// Each block's 128-col span lies in ONE (which,head): o = which*2048+h*128+d.
//   which=0 -> Qr[bh][t][d] (RoPE, pre-scaled 1/sqrt(128))
//   which=1 -> Kr[bh][t][d] (RoPE)
//   which=2 -> Vt[bh][d][t] (transposed, u64-packed over 4 consecutive t)
// RoPE pair partner d^1 is in adjacent lane -> __shfl_xor(v,1).
// Removes the 96MB qkv store + 96MB re-read + rope_reshape dispatch.
__global__ __launch_bounds__(256, 2) void gemm_qkv_rope(const u16* __restrict__ A,
                                                        const u16* __restrict__ B,
                                                        const float* __restrict__ cosb,
                                                        const float* __restrict__ sinb,
                                                        u16* __restrict__ Qr,
                                                        u16* __restrict__ Kr,
                                                        u16* __restrict__ Vt) {
  const int K = 2048;
  __shared__ __attribute__((aligned(16))) u16 As[128 * 32];
  __shared__ __attribute__((aligned(16))) u16 Bs[128 * 32];
  const int tid  = threadIdx.x;
  const int wave = tid >> 6, lane = tid & 63;
  const int quad = lane >> 4, l16 = lane & 15;
  const int m0 = blockIdx.y * 128, n0 = blockIdx.x * 128;
  const int wr = wave >> 1, wc = wave & 1;
  const int lrow = lane >> 2;        // 0..15 row within 16-row chunk
  const int lcol = (lane & 3) * 8;   // element col within BK
  f32x4 acc[4][4] = {};

  const size_t Abase = (size_t)(m0 + wave * 32 + lrow) * K + lcol;
  const size_t Bbase = (size_t)(n0 + wave * 32 + lrow) * K + lcol;

  for (int k0 = 0; k0 < K; k0 += 32) {
    gload16(A + Abase + k0,                 &As[(wave * 32) * 32]);
    gload16(A + Abase + (size_t)16 * K + k0, &As[(wave * 32 + 16) * 32]);
    gload16(B + Bbase + k0,                 &Bs[(wave * 32) * 32]);
    gload16(B + Bbase + (size_t)16 * K + k0, &Bs[(wave * 32 + 16) * 32]);
    __syncthreads();
    short8 a[4], b[4];
#pragma unroll
    for (int rt = 0; rt < 4; rt++)
      a[rt] = *(const short8*)&As[(wr * 64 + rt * 16 + l16) * 32 + quad * 8];
#pragma unroll
    for (int ct = 0; ct < 4; ct++)
      b[ct] = *(const short8*)&Bs[(wc * 64 + ct * 16 + l16) * 32 + quad * 8];
#pragma unroll
    for (int rt = 0; rt < 4; rt++)
#pragma unroll
      for (int ct = 0; ct < 4; ct++)
        acc[rt][ct] = __builtin_amdgcn_mfma_f32_16x16x32_bf16(a[rt], b[ct], acc[rt][ct], 0, 0, 0);
    __syncthreads();
  }

  // fused epilogue (C-layout col=lane&15, row=quad*4+reg — m89/m91)
  const int which = n0 >> 11;          // 0=Q 1=K 2=V (block-uniform)
  const int h = (n0 >> 7) & 15;
  if (which == 2) {
    // V: Vt[(bh*128+d)][t], pack 4 consecutive t (r=0..3) into u64
#pragma unroll
    for (int rt = 0; rt < 4; rt++) {
#pragma unroll
      for (int ct = 0; ct < 4; ct++) {
        const int d = wc * 64 + ct * 16 + l16;
        const int row0 = m0 + wr * 64 + rt * 16 + quad * 4;
        const int b = row0 >> 11, tt0 = row0 & 2047;
        u64 pk = (u64)f2bf(acc[rt][ct][0]) | ((u64)f2bf(acc[rt][ct][1]) << 16) |
                 ((u64)f2bf(acc[rt][ct][2]) << 32) | ((u64)f2bf(acc[rt][ct][3]) << 48);
        *(u64*)(Vt + ((size_t)((b * 16 + h) * 128 + d)) * 2048 + tt0) = pk;
      }
    }
  } else {
    u16* dst = which ? Kr : Qr;
    const float qs = which ? 1.0f : 0.08838834764831845f;  // 1/sqrt(128) on Q
#pragma unroll
    for (int rt = 0; rt < 4; rt++) {
#pragma unroll
      for (int ct = 0; ct < 4; ct++) {
        const int d = wc * 64 + ct * 16 + l16;
        const float sgn = (d & 1) ? 1.0f : -1.0f;
        const int ci = d >> 1;
#pragma unroll
        for (int r = 0; r < 4; r++) {
          const int row = m0 + wr * 64 + rt * 16 + quad * 4 + r;
          const int b = row >> 11, tt = row & 2047;
          const float c = cosb[tt * 64 + ci], s = sinb[tt * 64 + ci];
          const float v = acc[rt][ct][r];
          const float p = __shfl_xor(v, 1);          // pair partner (d^1)
          const float rot = (v * c + sgn * p * s) * qs;
          dst[((size_t)((b * 16 + h) * 2048 + tt)) * 128 + d] = f2bf(rot);
        }
      }
    }
  }
}

// ---------------------------------------------------------------- NT GEMM (proj)
// C[M,N] = A[M,K] * B[N,K]^T, bf16 inputs, fp32 accum, f32 out + bias.
// R6-exact (proven-good m97 structure, at its ceiling).
__global__ __launch_bounds__(256, 2) void gemm_bt(const u16* __restrict__ A,
                                                  const u16* __restrict__ B,
                                                  float* __restrict__ C,
                                                  int M, int N, int K,
                                                  const float* __restrict__ bias) {
  __shared__ __attribute__((aligned(16))) u16 As[128 * 32];
  __shared__ __attribute__((aligned(16))) u16 Bs[128 * 32];
  const int tid  = threadIdx.x;
  const int wave = tid >> 6, lane = tid & 63;
  const int quad = lane >> 4, l16 = lane & 15;
  const int m0 = blockIdx.y * 128, n0 = blockIdx.x * 128;
  const int wr = wave >> 1, wc = wave & 1;
  const int lrow = lane >> 2;        // 0..15 row within 16-row chunk
  const int lcol = (lane & 3) * 8;   // element col within BK
  f32x4 acc[4][4] = {};

  const size_t Abase = (size_t)(m0 + wave * 32 + lrow) * K + lcol;
  const size_t Bbase = (size_t)(n0 + wave * 32 + lrow) * K + lcol;

  for (int k0 = 0; k0 < K; k0 += 32) {
    gload16(A + Abase + k0,                 &As[(wave * 32) * 32]);
    gload16(A + Abase + (size_t)16 * K + k0, &As[(wave * 32 + 16) * 32]);
    gload16(B + Bbase + k0,                 &Bs[(wave * 32) * 32]);
    gload16(B + Bbase + (size_t)16 * K + k0, &Bs[(wave * 32 + 16) * 32]);
    __syncthreads();
    short8 a[4], b[4];
#pragma unroll
    for (int rt = 0; rt < 4; rt++)
      a[rt] = *(const short8*)&As[(wr * 64 + rt * 16 + l16) * 32 + quad * 8];
#pragma unroll
    for (int ct = 0; ct < 4; ct++)
      b[ct] = *(const short8*)&Bs[(wc * 64 + ct * 16 + l16) * 32 + quad * 8];
#pragma unroll
    for (int rt = 0; rt < 4; rt++)
#pragma unroll
      for (int ct = 0; ct < 4; ct++)
        acc[rt][ct] = __builtin_amdgcn_mfma_f32_16x16x32_bf16(a[rt], b[ct], acc[rt][ct], 0, 0, 0);
    __syncthreads();
  }
  // epilogue: C-layout col=lane&15, row=quad*4+reg (verified m89/m91)
#pragma unroll
  for (int rt = 0; rt < 4; rt++) {
#pragma unroll
    for (int ct = 0; ct < 4; ct++) {
      const int col = n0 + wc * 64 + ct * 16 + l16;
      float bv = bias[col];
#pragma unroll
      for (int r = 0; r < 4; r++) {
        const int row = m0 + wr * 64 + rt * 16 + quad * 4 + r;
        C[(size_t)row * N + col] = acc[rt][ct][r] + bv;
      }
    }
  }
}

// ---------------------------------------------------------------- flash attention
// R6-exact (best verified: ~237us). One block = 128 Q rows (4 waves x 32),
// 16 KV blocks of 128. K/V via global_load_lds fragment-chunked staging;
// P aliases K region with PADDED stride 136 el (R6 verified, conflict fix);
// all hot-loop addressing AFFINE (rounds 1/2/4: XOR here => spill cliff).
// T13 defer-max (R5/R6 verified): gated max-reduce + rescale.
__global__ __launch_bounds__(256, 2) void flash_attn(const u16* __restrict__ Q,
                                                     const u16* __restrict__ K,
                                                     const u16* __restrict__ Vt,
                                                     u16* __restrict__ Out) {
  __shared__ __attribute__((aligned(16))) char lds[67584];  // K 32KB | gap | V 32KB
  u16* Klds = (u16*)lds;                  // 32 chunks x 512 el
  u16* Vlds = (u16*)(lds + 34816);        // 32 chunks x 512 el
  const int qb = blockIdx.x;   // 0..15
  const int bh = blockIdx.y;   // 0..63
  const int tid = threadIdx.x;
  const int wave = tid >> 6, lane = tid & 63;
  const int quad = lane >> 4, l16 = lane & 15;
  const int lrow4 = lane >> 2, lcol8 = (lane & 3) * 8;
  const u16* Qh = Q + (size_t)bh * 2048 * 128;
  const u16* Kh = K + (size_t)bh * 2048 * 128;
  const u16* Vh = Vt + (size_t)bh * 128 * 2048;

  // Q fragments (A-layout: m=lane&15, k=quad*8+j), kept in regs, pre-scaled
  short8 qf[2][4];
#pragma unroll
  for (int rt = 0; rt < 2; rt++)
#pragma unroll
    for (int kk = 0; kk < 4; kk++)
      qf[rt][kk] = *(const short8*)(Qh + (size_t)(qb * 128 + wave * 32 + rt * 16 + l16) * 128 + kk * 32 + quad * 8);

  f32x4 o[2][8] = {};
  float mrow[2][4], lrowv[2][4];
#pragma unroll
  for (int rt = 0; rt < 2; rt++)
#pragma unroll
    for (int r = 0; r < 4; r++) { mrow[rt][r] = -1e30f; lrowv[rt][r] = 0.f; }

  for (int kb = 0; kb < 16; kb++) {
    __syncthreads();  // all P/V reads from previous iter done
#pragma unroll
    for (int c = 0; c < 8; c++) {
      int ch = wave * 8 + c;
      int tbb = ch >> 2, kk = ch & 3;  // 16-row group, 32-k group
      gload16(Kh + (size_t)(kb * 128 + tbb * 16 + lrow4) * 128 + kk * 32 + lcol8, &Klds[ch * 512]);
      gload16(Vh + (size_t)(tbb * 16 + lrow4) * 2048 + kb * 128 + kk * 32 + lcol8, &Vlds[ch * 512]);
    }
    __syncthreads();  // K/V staged

    // S = Q K^T  (32 rows x 128 cols per wave)
    f32x4 s[2][8];
#pragma unroll
    for (int nt = 0; nt < 8; nt++) {
      short8 kf[4];
#pragma unroll
      for (int kk = 0; kk < 4; kk++)
        kf[kk] = *(const short8*)&Klds[(nt * 4 + kk) * 512 + l16 * 32 + quad * 8];
#pragma unroll
      for (int rt = 0; rt < 2; rt++) {
        f32x4 a = {};
#pragma unroll
        for (int kk = 0; kk < 4; kk++)
          a = __builtin_amdgcn_mfma_f32_16x16x32_bf16(qf[rt][kk], kf[kk], a, 0, 0, 0);
        s[rt][nt] = a;
      }
    }

    // online softmax with T13 defer-max (C-layout: row=quad*4+reg, col=nt*16+l16);
    // gate on the pre-reduce local max: skips the 4-shuffle reduce too.
#pragma unroll
    for (int rt = 0; rt < 2; rt++)
#pragma unroll
      for (int r = 0; r < 4; r++) {
        float mx8 = s[rt][0][r];
#pragma unroll
        for (int nt = 1; nt < 8; nt++) mx8 = fmaxf(mx8, s[rt][nt][r]);
        if (__any(mx8 > mrow[rt][r] + 8.0f)) {
          float mx = mx8;
          mx = fmaxf(mx, __shfl_xor(mx, 1));
          mx = fmaxf(mx, __shfl_xor(mx, 2));
          mx = fmaxf(mx, __shfl_xor(mx, 4));
          mx = fmaxf(mx, __shfl_xor(mx, 8));
          float mnew = fmaxf(mrow[rt][r], mx);
          float alpha = __expf(mrow[rt][r] - mnew);
          mrow[rt][r] = mnew;
          lrowv[rt][r] *= alpha;
#pragma unroll
          for (int dt = 0; dt < 8; dt++) o[rt][dt][r] *= alpha;
        }
        float m = mrow[rt][r];
        float sum = 0.f;
#pragma unroll
        for (int nt = 0; nt < 8; nt++) {
          float p = __expf(s[rt][nt][r] - m);   // bounded by e^8
          s[rt][nt][r] = p;
          sum += p;
        }
        sum += __shfl_xor(sum, 1);
        sum += __shfl_xor(sum, 2);
        sum += __shfl_xor(sum, 4);
        sum += __shfl_xor(sum, 8);
        lrowv[rt][r] += sum;
      }

    __syncthreads();  // all waves done reading Klds before P overwrite
    // P: 32 rows x 128 k per wave, PADDED stride 136 el (affine: shl+add)
    u16* P = (u16*)lds + wave * 4352;   // 8704B/wave, 4 waves = 34816B
#pragma unroll
    for (int rt = 0; rt < 2; rt++)
#pragma unroll
      for (int nt = 0; nt < 8; nt++)
#pragma unroll
        for (int r = 0; r < 4; r++)
          P[(rt * 16 + quad * 4 + r) * 136 + nt * 16 + l16] = f2bf(s[rt][nt][r]);
    __syncthreads();  // P visible

    // O += P V  (A = P from LDS, B = V fragments)
#pragma unroll
    for (int kk = 0; kk < 4; kk++) {
      short8 pf[2];
#pragma unroll
      for (int rt = 0; rt < 2; rt++)
        pf[rt] = *(const short8*)&P[(rt * 16 + l16) * 136 + kk * 32 + quad * 8];
#pragma unroll
      for (int dt = 0; dt < 8; dt++) {
        short8 vf = *(const short8*)&Vlds[(dt * 4 + kk) * 512 + l16 * 32 + quad * 8];
#pragma unroll
        for (int rt = 0; rt < 2; rt++)
          o[rt][dt] = __builtin_amdgcn_mfma_f32_16x16x32_bf16(pf[rt], vf, o[rt][dt], 0, 0, 0);
      }
    }
  }

  // epilogue: divide by l, store attn_out [b*T+t][h*128+d] bf16
  const int b = bh >> 4, h = bh & 15;
#pragma unroll
  for (int rt = 0; rt < 2; rt++) {
    float inv[4];
#pragma unroll
    for (int r = 0; r < 4; r++) inv[r] = 1.0f / lrowv[rt][r];
#pragma unroll
    for (int dt = 0; dt < 8; dt++) {
      int d = dt * 16 + l16;
#pragma unroll
      for (int r = 0; r < 4; r++) {
        int t = qb * 128 + wave * 32 + rt * 16 + quad * 4 + r;
        Out[((size_t)(b * 2048 + t)) * 2048 + h * 128 + d] = f2bf(o[rt][dt][r] * inv[r]);
      }
    }
  }
}

// ---------------------------------------------------------------- launch
extern "C" void kernel_launch(void* const* d_in, const int* in_sizes, int n_in,
                              void* d_out, int out_size, void* d_ws, size_t ws_size,
                              hipStream_t stream) {
  const float* x      = (const float*)d_in[0];
  const float* w_qkv  = (const float*)d_in[1];
  const float* w_proj = (const float*)d_in[2];
  const float* b_proj = (const float*)d_in[3];
  const float* cosb   = (const float*)d_in[4];
  const float* sinb   = (const float*)d_in[5];
  char* ws = (char*)d_ws;
  const size_t MB = 1024 * 1024;
  // layout (no qkv intermediate anymore), peak 192 MB:
  u16* xb   = (u16*)(ws + 0);          // x bf16, 32MB (dead after GEMM1)
  u16* wqb  = (u16*)(ws + 32 * MB);    // w_qkv bf16, 24MB (dead after GEMM1)
  u16* wpb  = (u16*)(ws + 56 * MB);    // w_proj bf16, 8MB
  u16* Qr   = (u16*)(ws + 64 * MB);    // 32MB
  u16* Kr   = (u16*)(ws + 96 * MB);    // 32MB
  u16* Vt   = (u16*)(ws + 128 * MB);   // 32MB
  u16* attn = (u16*)(ws + 160 * MB);   // 32MB

  cvt_kernel<<<16384, 256, 0, stream>>>(x, xb);        // 16.8M elems
  cvt_kernel<<<12288, 256, 0, stream>>>(w_qkv, wqb);   // 12.6M
  cvt_kernel<<<4096, 256, 0, stream>>>(w_proj, wpb);   // 4.2M

  gemm_qkv_rope<<<dim3(48, 64), 256, 0, stream>>>(xb, wqb, cosb, sinb, Qr, Kr, Vt);
  flash_attn<<<dim3(16, 64), 256, 0, stream>>>(Qr, Kr, Vt, attn);
  gemm_bt<<<dim3(16, 64), 256, 0, stream>>>(attn, wpb, (float*)d_out, 8192, 2048, 2048, b_proj);
}